// Round 18
// baseline (212.457 us; speedup 1.0000x reference)
//
#include <hip/hip_runtime.h>
#include <hip/hip_fp16.h>

#define NN 512
#define DD 768

typedef _Float16 half8 __attribute__((ext_vector_type(8)));
typedef _Float16 half4 __attribute__((ext_vector_type(4)));
typedef _Float16 half2v __attribute__((ext_vector_type(2)));
typedef float f32x4 __attribute__((ext_vector_type(4)));

__device__ __forceinline__ int f2ord(float f) {
  int i = __float_as_int(f);
  return i < 0 ? (i ^ 0x7fffffff) : i;
}
__device__ __forceinline__ float ord2f(int i) {
  return __int_as_float(i < 0 ? (i ^ 0x7fffffff) : i);
}

// async global->LDS, 16B per lane; LDS dest = wave-uniform base + lane*16 implicit
__device__ __forceinline__ void glds16(const void* g, void* l) {
  __builtin_amdgcn_global_load_lds((const __attribute__((address_space(1))) void*)g,
                                   (__attribute__((address_space(3))) void*)l, 16, 0, 0);
}

// ---------------- K1: row-normalize + fp16 cast (+ block 0 zeroes counters) ----------
__global__ __launch_bounds__(256) void k_norm(const float* __restrict__ f1,
                                              const float* __restrict__ f2,
                                              __half* __restrict__ xn,
                                              __half* __restrict__ yn,
                                              int* __restrict__ cnt) {
  if (blockIdx.x == 0) {               // zero all barrier counters (visible via kernel boundary)
    int t = threadIdx.x;
    if (t < 64) { cnt[t * 16] = 0; cnt[1024 + t * 16] = 0; }
    if (t == 0) cnt[2048] = 0;
  }
  int row = blockIdx.x * 4 + (threadIdx.x >> 6);
  int lane = threadIdx.x & 63;
  int r = row & 32767;
  const float* src = (row < 32768 ? f1 : f2) + (size_t)r * DD;
  __half* dst = (row < 32768 ? xn : yn) + (size_t)r * DD;
  f32x4 v0 = *(const f32x4*)(src + lane * 4);
  f32x4 v1 = *(const f32x4*)(src + lane * 4 + 256);
  f32x4 v2 = *(const f32x4*)(src + lane * 4 + 512);
  float s = v0[0]*v0[0] + v0[1]*v0[1] + v0[2]*v0[2] + v0[3]*v0[3]
          + v1[0]*v1[0] + v1[1]*v1[1] + v1[2]*v1[2] + v1[3]*v1[3]
          + v2[0]*v2[0] + v2[1]*v2[1] + v2[2]*v2[2] + v2[3]*v2[3];
  #pragma unroll
  for (int m = 1; m < 64; m <<= 1) s += __shfl_xor(s, m, 64);
  float f = 1.0f / (sqrtf(s) + 1e-12f);
  union U { __half2 h2[2]; uint2 u; };
  U u0, u1, u2;
  u0.h2[0] = __floats2half2_rn(v0[0]*f, v0[1]*f); u0.h2[1] = __floats2half2_rn(v0[2]*f, v0[3]*f);
  u1.h2[0] = __floats2half2_rn(v1[0]*f, v1[1]*f); u1.h2[1] = __floats2half2_rn(v1[2]*f, v1[3]*f);
  u2.h2[0] = __floats2half2_rn(v2[0]*f, v2[1]*f); u2.h2[1] = __floats2half2_rn(v2[2]*f, v2[3]*f);
  *(uint2*)(dst + lane * 4)       = u0.u;
  *(uint2*)(dst + lane * 4 + 256) = u1.u;
  *(uint2*)(dst + lane * 4 + 512) = u2.u;
}

// ---------------- K2: FUSED gemm + threshold + 30-iter IPOT + final reduce ----------
// r18 deltas vs r15: (1) loop exchange uses READER-SPIN (all 256 readers poll the
// counter and read partials on detect -- removes one syncthreads + detect->read hop);
// (2) minmax barrier settle OVERLAPPED with the raw-C relayout (L1-add early,
// relayout thr-independent raw C, then L1-spin/L2, then A=exp applied in registers).
#define FOR16(X) X(0) X(1) X(2) X(3) X(4) X(5) X(6) X(7) X(8) X(9) X(10) X(11) X(12) X(13) X(14) X(15)

#define AGLD(p) __hip_atomic_load((p), __ATOMIC_RELAXED, __HIP_MEMORY_SCOPE_AGENT)
#define AGST(p, v) __hip_atomic_store((p), (v), __ATOMIC_RELAXED, __HIP_MEMORY_SCOPE_AGENT)
#define AGADD(p) __hip_atomic_fetch_add((p), 1, __ATOMIC_RELAXED, __HIP_MEMORY_SCOPE_AGENT)

struct IpotLds {
  float xs[128];
  float ys[NN];
  _Float16 zs[NN];
  _Float16 csh[8][520];
  float wred[8];
};
union MainLds {
  _Float16 Bs[2][16384];   // 64KB: [buf][row 0..511][4 slots x 8 halfs], row stride 64B
  _Float16 At[4][8192];    // 64KB: transpose regions (16KB per wave-slot)
  float mm[16];
  int mmi[16];
  IpotLds ip;
};

__global__ __launch_bounds__(512, 2) void k_main(const __half* __restrict__ xn,
                                                 const __half* __restrict__ yn,
                                                 int* __restrict__ cnt,
                                                 int* __restrict__ gmm,
                                                 unsigned* __restrict__ gpart,
                                                 float* __restrict__ gdist,
                                                 float* __restrict__ out) {
  __shared__ __align__(16) MainLds u;
  const int blk = blockIdx.x;
  const int b = blk & 63, qq = blk >> 6;
  const int tid = threadIdx.x;
  const int sv = tid >> 6, lane = tid & 63;
  const int fr = lane & 15;
  const int r0 = sv * 16;
  const int c0 = lane * 8;
  const int kg = lane >> 4;                        // k-group 0..3
  const int g8 = kg * 8;                           // k-offset in halfs (global A reads)
  const int rslot = (kg ^ ((fr >> 1) & 3)) * 8;    // swizzled B-read slot (halfs)
  const __half* xnb = xn + ((size_t)b * NN + qq * 128 + sv * 16) * DD;  // wave's 16 rows
  const __half* ynb = yn + (size_t)b * NN * DD;

  // ================= GEMM: acc[c] = C-tile rows 16sv.., cols 16c.. =================
  f32x4 acc[32] = {};
  const int srcq = ((lane & 3) ^ ((lane >> 3) & 3)) * 8;   // swizzle via source chunk
#define STAGE(bf, kk) { \
    _Pragma("unroll") \
    for (int j = 0; j < 4; ++j) { \
      const __half* ys_ = ynb + (size_t)(128 * j + sv * 16 + (lane >> 2)) * DD + (kk) + srcq; \
      glds16(ys_, (char*)u.Bs[bf] + j * 8192 + sv * 1024); \
    } }
  int buf = 0;
  STAGE(0, 0)
  half8 afp = *(const half8*)(xnb + (size_t)fr * DD + g8);
  for (int kk = 0; kk < DD; kk += 32) {
    __syncthreads();                       // drains vmcnt: Bs[buf] resident
    if (kk + 32 < DD) STAGE(buf ^ 1, kk + 32)
    half8 afc = afp;
    if (kk + 32 < DD) afp = *(const half8*)(xnb + (size_t)fr * DD + (kk + 32) + g8);
    #pragma unroll
    for (int c = 0; c < 32; ++c) {
      half8 bf = *(const half8*)(&u.Bs[buf][(16 * c + fr) * 32 + rslot]);
      acc[c] = __builtin_amdgcn_mfma_f32_16x16x32_f16(afc, bf, acc[c], 0, 0, 0);
    }
    buf ^= 1;
  }

  // ================= local min/max -> gmm; L1 add EARLY =================
  float vmin = 1e30f, vmax = -1e30f;
  #pragma unroll
  for (int c = 0; c < 32; ++c) {
    #pragma unroll
    for (int r2 = 0; r2 < 4; ++r2) {
      float val = 1.0f - acc[c][r2];
      vmin = fminf(vmin, val); vmax = fmaxf(vmax, val);
    }
  }
  #pragma unroll
  for (int m = 1; m < 64; m <<= 1) {
    vmin = fminf(vmin, __shfl_xor(vmin, m, 64));
    vmax = fmaxf(vmax, __shfl_xor(vmax, m, 64));
  }
  __syncthreads();                          // Bs dead; union repurposed
  if (lane == 0) { u.mm[sv] = vmin; u.mm[8 + sv] = vmax; }
  __syncthreads();
  if (tid == 0) {
    float bm = u.mm[0], bx = u.mm[8];
    #pragma unroll
    for (int g = 1; g < 8; ++g) { bm = fminf(bm, u.mm[g]); bx = fmaxf(bx, u.mm[8 + g]); }
    AGST(gmm + blk, (unsigned)f2ord(bm));
    AGST(gmm + 256 + blk, (unsigned)f2ord(bx));
  }
  __syncthreads();                          // gmm stores drained (all waves)
  int* c1p = cnt + 1024 + b * 16;
  if (tid == 0) AGADD(c1p);                 // L1 add; spin deferred past relayout

  // ================= raw-C relayout (thr-independent) overlaps barrier settle ======
#define DECLAM(r) half8 A##r, M##r;
  FOR16(DECLAM)

#define TWRITE { \
    _Float16* reg_ = u.At[sv & 3]; \
    const int q_ = lane >> 4; \
    _Pragma("unroll") \
    for (int c = 0; c < 32; ++c) { \
      _Pragma("unroll") \
      for (int r2 = 0; r2 < 4; ++r2) { \
        float val_ = 1.0f - acc[c][r2]; \
        int off_ = (((4 * q_ + r2) * 1024 + (16 * c + fr) * 2) ^ (q_ << 4)) >> 1; \
        reg_[off_] = (_Float16)val_; \
      } \
    } }

#define TREAD(r) { \
    A##r = *(const half8*)((const char*)u.At[sv & 3] + \
            (((r) * 1024 + lane * 16) ^ ((((r) >> 2) & 3) << 4))); }

  __syncthreads();
  if (sv < 4) TWRITE
  __syncthreads();
  if (sv < 4) { FOR16(TREAD) }
  __syncthreads();
  if (sv >= 4) TWRITE
  __syncthreads();
  if (sv >= 4) { FOR16(TREAD) }
  __syncthreads();

  // ================= finish global minmax barrier, reduce thr =================
  if (tid == 0) {
    while (__hip_atomic_load(c1p, __ATOMIC_RELAXED, __HIP_MEMORY_SCOPE_AGENT) < 4)
      __builtin_amdgcn_s_sleep(1);
    if (qq == 0) AGADD(cnt + 2048);
    while (__hip_atomic_load(cnt + 2048, __ATOMIC_RELAXED, __HIP_MEMORY_SCOPE_AGENT) < 64)
      __builtin_amdgcn_s_sleep(8);
  }
  __syncthreads();
  {
    int mo = (int)AGLD(gmm + tid);          // tid<256: min-ords; tid>=256: max-ords
    #pragma unroll
    for (int m = 1; m < 64; m <<= 1) {
      int o = __shfl_xor(mo, m, 64);
      mo = (sv < 4) ? (mo < o ? mo : o) : (mo > o ? mo : o);
    }
    if (lane == 0) u.mmi[sv] = mo;          // At dead (TREAD complete)
  }
  __syncthreads();
  int gmnord = u.mmi[0], gmxord = u.mmi[4];
  #pragma unroll
  for (int g = 1; g < 4; ++g) {
    gmnord = gmnord < u.mmi[g] ? gmnord : u.mmi[g];
    gmxord = gmxord > u.mmi[4 + g] ? gmxord : u.mmi[4 + g];
  }
  const float gmn = ord2f(gmnord);
  const float gmx = ord2f(gmxord);
  const float thr = gmn + 0.1f * (gmx - gmn);

  // ================= A = exp(-2 relu(Craw - thr)) in registers; M = A ==============
#define EXPA(r) { \
    A##r.s0 = (_Float16)__expf(-2.0f * fmaxf((float)A##r.s0 - thr, 0.0f)); \
    A##r.s1 = (_Float16)__expf(-2.0f * fmaxf((float)A##r.s1 - thr, 0.0f)); \
    A##r.s2 = (_Float16)__expf(-2.0f * fmaxf((float)A##r.s2 - thr, 0.0f)); \
    A##r.s3 = (_Float16)__expf(-2.0f * fmaxf((float)A##r.s3 - thr, 0.0f)); \
    A##r.s4 = (_Float16)__expf(-2.0f * fmaxf((float)A##r.s4 - thr, 0.0f)); \
    A##r.s5 = (_Float16)__expf(-2.0f * fmaxf((float)A##r.s5 - thr, 0.0f)); \
    A##r.s6 = (_Float16)__expf(-2.0f * fmaxf((float)A##r.s6 - thr, 0.0f)); \
    A##r.s7 = (_Float16)__expf(-2.0f * fmaxf((float)A##r.s7 - thr, 0.0f)); \
    M##r = A##r; }
  FOR16(EXPA)

  // ================= ipot state init =================
  if (tid < 256) *(half2v*)(u.ip.zs + 2 * tid) = (half2v){(_Float16)1.0f, (_Float16)1.0f};
  u.ip.ys[tid] = 1.0f;
  __syncthreads();

  int* mycnt = cnt + b * 16;

  // ================= 30 iterations (reader-spin exchange; UPDM overlapped) =========
  #pragma unroll 1
  for (int t = 1; t <= 30; ++t) {
    half8 zv = *(const half8*)(u.ip.zs + c0);
    float rp16[16];
#define ROWP(r) { \
      half8 p = M##r * zv; \
      half4 q = p.lo + p.hi; \
      half2v q2 = q.lo + q.hi; \
      rp16[r] = (float)q2.x + (float)q2.y; }
    FOR16(ROWP)
    float c8[8];
    #pragma unroll
    for (int i = 0; i < 8; ++i) {
      float keep = (lane & 1) ? rp16[2*i+1] : rp16[2*i];
      float send = (lane & 1) ? rp16[2*i]   : rp16[2*i+1];
      c8[i] = keep + __shfl_xor(send, 1, 64);
    }
    float c4[4];
    #pragma unroll
    for (int i = 0; i < 4; ++i) {
      float keep = (lane & 2) ? c8[2*i+1] : c8[2*i];
      float send = (lane & 2) ? c8[2*i]   : c8[2*i+1];
      c4[i] = keep + __shfl_xor(send, 2, 64);
    }
    float d2[2];
    #pragma unroll
    for (int i = 0; i < 2; ++i) {
      float keep = (lane & 4) ? c4[2*i+1] : c4[2*i];
      float send = (lane & 4) ? c4[2*i]   : c4[2*i+1];
      d2[i] = keep + __shfl_xor(send, 4, 64);
    }
    float c1;
    {
      float keep = (lane & 8) ? d2[1] : d2[0];
      float send = (lane & 8) ? d2[0] : d2[1];
      c1 = keep + __shfl_xor(send, 8, 64);
    }
    c1 += __shfl_xor(c1, 16, 64);
    c1 += __shfl_xor(c1, 32, 64);
    if (lane < 16) u.ip.xs[r0 + lane] = 1.0f / c1;
    half8 cac = (half8)(_Float16)0.0f;
#define COLP(r) { _Float16 xh = (_Float16)u.ip.xs[r0 + r]; cac += M##r * xh; }
    FOR16(COLP)
    *(half8*)(&u.ip.csh[sv][c0]) = cac;
    __syncthreads();
    // ---- reduce + ISSUE partial stores, UPDM covers flight ----
    unsigned* gp = gpart + ((size_t)((t & 1) * 256 + blk) * 256);
    if (tid < 256) {
      float a0 = 0.0f, a1 = 0.0f;
      #pragma unroll
      for (int g = 0; g < 8; ++g) {
        half2v pv = *(const half2v*)(&u.ip.csh[g][2 * tid]);
        a0 += (float)pv.x; a1 += (float)pv.y;
      }
      __half2 ph = __floats2half2_rn(a0, a1);
      AGST(gp + tid, *reinterpret_cast<unsigned*>(&ph));
    }
#define UPDM(r) M##r *= A##r;
    if (t < 30) { FOR16(UPDM) }             // register-only; overlaps store flight
    __syncthreads();  // vmcnt(0) before s_barrier: all stores at coherent point
    if (tid == 0) AGADD(mycnt);
    if (tid < 256) {                        // READER-SPIN: poll, then read immediately
      while (__hip_atomic_load(mycnt, __ATOMIC_RELAXED, __HIP_MEMORY_SCOPE_AGENT) < 4 * t)
        __builtin_amdgcn_s_sleep(1);
      float a0 = 0.0f, a1 = 0.0f;
      #pragma unroll
      for (int q2 = 0; q2 < 4; ++q2) {
        unsigned v = AGLD(gpart + ((size_t)((t & 1) * 256 + b + 64 * q2) * 256) + tid);
        __half2 h = *reinterpret_cast<__half2*>(&v);
        float2 fv = __half22float2(h);
        a0 += fv.x; a1 += fv.y;
      }
      float yo0 = u.ip.ys[2 * tid], yo1 = u.ip.ys[2 * tid + 1];
      float y0 = 1.0f / a0;
      float y1 = 1.0f / a1;
      *(half2v*)(u.ip.zs + 2 * tid) = (half2v){(_Float16)(y0 * y0 / yo0), (_Float16)(y1 * y1 / yo1)};
      u.ip.ys[2 * tid] = y0; u.ip.ys[2 * tid + 1] = y1;
    }
    __syncthreads();
  }

  // ================= dist partial: C' = -0.5 ln A (regs) =================
  float contrib = 0.0f;
#define FINP(r) { \
    float rowacc = 0.0f; \
    rowacc += -0.34657359f * __log2f((float)A##r.s0) * (float)M##r.s0 * u.ip.ys[c0 + 0]; \
    rowacc += -0.34657359f * __log2f((float)A##r.s1) * (float)M##r.s1 * u.ip.ys[c0 + 1]; \
    rowacc += -0.34657359f * __log2f((float)A##r.s2) * (float)M##r.s2 * u.ip.ys[c0 + 2]; \
    rowacc += -0.34657359f * __log2f((float)A##r.s3) * (float)M##r.s3 * u.ip.ys[c0 + 3]; \
    rowacc += -0.34657359f * __log2f((float)A##r.s4) * (float)M##r.s4 * u.ip.ys[c0 + 4]; \
    rowacc += -0.34657359f * __log2f((float)A##r.s5) * (float)M##r.s5 * u.ip.ys[c0 + 5]; \
    rowacc += -0.34657359f * __log2f((float)A##r.s6) * (float)M##r.s6 * u.ip.ys[c0 + 6]; \
    rowacc += -0.34657359f * __log2f((float)A##r.s7) * (float)M##r.s7 * u.ip.ys[c0 + 7]; \
    contrib += rowacc * u.ip.xs[r0 + r]; }
  FOR16(FINP)
  #pragma unroll
  for (int m = 1; m < 64; m <<= 1) contrib += __shfl_xor(contrib, m, 64);
  if (lane == 0) u.ip.wred[sv] = contrib;
  __syncthreads();
  if (tid == 0) {
    float s2 = 0.0f;
    #pragma unroll
    for (int g = 0; g < 8; ++g) s2 += u.ip.wred[g];
    AGST(gdist + blk, s2);
  }
  // ================= merged final: global barrier -> block 0 reduces =================
  __syncthreads();                          // drains tid0's gdist store
  if (tid == 0) AGADD(cnt + 2048);          // counter now reaches 64 + 256 = 320
  if (blk == 0) {
    if (tid == 0) {
      while (__hip_atomic_load(cnt + 2048, __ATOMIC_RELAXED, __HIP_MEMORY_SCOPE_AGENT) < 320)
        __builtin_amdgcn_s_sleep(8);
    }
    __syncthreads();
    if (tid < 64) {
      float v = AGLD(gdist + tid) + AGLD(gdist + tid + 64)
              + AGLD(gdist + tid + 128) + AGLD(gdist + tid + 192);
      #pragma unroll
      for (int m = 1; m < 64; m <<= 1) v += __shfl_xor(v, m, 64);
      if (tid == 0) out[0] = -v * (1.0f / (64.0f * 512.0f));
    }
  }
}

extern "C" void kernel_launch(void* const* d_in, const int* in_sizes, int n_in,
                              void* d_out, int out_size, void* d_ws, size_t ws_size,
                              hipStream_t stream) {
  const float* f1 = (const float*)d_in[0];
  const float* f2 = (const float*)d_in[1];
  char* ws = (char*)d_ws;
  __half* xn   = (__half*)(ws + 0);                  // 50,331,648 B
  __half* yn   = (__half*)(ws + 50331648);           // 50,331,648 B
  unsigned* gpart = (unsigned*)(ws + 100663296);     // 512KB fp16-packed partials
  int*   cnt   = (int*)(ws + 167772160);             // loop cnts | minmax L1 | [2048] global
  int*   gmm   = (int*)(ws + 167772160 + 16384);     // 512 ints block min/max
  float* gdist = (float*)(ws + 167772160 + 16384 + 2048);  // 256 floats

  k_norm<<<16384, 256, 0, stream>>>(f1, f2, xn, yn, cnt);
  k_main<<<256, 512, 0, stream>>>(xn, yn, cnt, (int*)gmm, gpart, gdist, (float*)d_out);
}

// Round 19
// 190.633 us; speedup vs baseline: 1.1145x; 1.1145x over previous
//
#include <hip/hip_runtime.h>
#include <hip/hip_fp16.h>

#define NN 512
#define DD 768

typedef _Float16 half8 __attribute__((ext_vector_type(8)));
typedef _Float16 half4 __attribute__((ext_vector_type(4)));
typedef _Float16 half2v __attribute__((ext_vector_type(2)));
typedef float f32x4 __attribute__((ext_vector_type(4)));

__device__ __forceinline__ int f2ord(float f) {
  int i = __float_as_int(f);
  return i < 0 ? (i ^ 0x7fffffff) : i;
}
__device__ __forceinline__ float ord2f(int i) {
  return __int_as_float(i < 0 ? (i ^ 0x7fffffff) : i);
}

// async global->LDS, 16B per lane; LDS dest = wave-uniform base + lane*16 implicit
__device__ __forceinline__ void glds16(const void* g, void* l) {
  __builtin_amdgcn_global_load_lds((const __attribute__((address_space(1))) void*)g,
                                   (__attribute__((address_space(3))) void*)l, 16, 0, 0);
}

// ---------------- K1: row-normalize + fp16 cast (+ block 0 zeroes counters) ----------
__global__ __launch_bounds__(256) void k_norm(const float* __restrict__ f1,
                                              const float* __restrict__ f2,
                                              __half* __restrict__ xn,
                                              __half* __restrict__ yn,
                                              int* __restrict__ cnt) {
  if (blockIdx.x == 0) {               // zero all barrier counters (visible via kernel boundary)
    int t = threadIdx.x;
    if (t < 64) { cnt[t * 16] = 0; cnt[1024 + t * 16] = 0; }
    if (t == 0) cnt[2048] = 0;
  }
  int row = blockIdx.x * 4 + (threadIdx.x >> 6);
  int lane = threadIdx.x & 63;
  int r = row & 32767;
  const float* src = (row < 32768 ? f1 : f2) + (size_t)r * DD;
  __half* dst = (row < 32768 ? xn : yn) + (size_t)r * DD;
  f32x4 v0 = *(const f32x4*)(src + lane * 4);
  f32x4 v1 = *(const f32x4*)(src + lane * 4 + 256);
  f32x4 v2 = *(const f32x4*)(src + lane * 4 + 512);
  float s = v0[0]*v0[0] + v0[1]*v0[1] + v0[2]*v0[2] + v0[3]*v0[3]
          + v1[0]*v1[0] + v1[1]*v1[1] + v1[2]*v1[2] + v1[3]*v1[3]
          + v2[0]*v2[0] + v2[1]*v2[1] + v2[2]*v2[2] + v2[3]*v2[3];
  #pragma unroll
  for (int m = 1; m < 64; m <<= 1) s += __shfl_xor(s, m, 64);
  float f = 1.0f / (sqrtf(s) + 1e-12f);
  union U { __half2 h2[2]; uint2 u; };
  U u0, u1, u2;
  u0.h2[0] = __floats2half2_rn(v0[0]*f, v0[1]*f); u0.h2[1] = __floats2half2_rn(v0[2]*f, v0[3]*f);
  u1.h2[0] = __floats2half2_rn(v1[0]*f, v1[1]*f); u1.h2[1] = __floats2half2_rn(v1[2]*f, v1[3]*f);
  u2.h2[0] = __floats2half2_rn(v2[0]*f, v2[1]*f); u2.h2[1] = __floats2half2_rn(v2[2]*f, v2[3]*f);
  *(uint2*)(dst + lane * 4)       = u0.u;
  *(uint2*)(dst + lane * 4 + 256) = u1.u;
  *(uint2*)(dst + lane * 4 + 512) = u2.u;
}

// ---------------- K2: FUSED gemm + threshold + 30-iter IPOT + final reduce ----------
// r15 configuration (measured best, 191-193 µs): 256 blocks x 512 threads, 1 blk/CU;
// b = blk&63 so a batch's 4 partner blocks share an XCD. Two-level minmax barrier;
// coalesced+swizzled B staging; fp16 exchange; UPDM overlapped; merged final.
// A/B-refuted alternatives: inbox-poll (r7), [row][q] B-layout (r12 +conflicts OK but
// -coalescing), scattered-XCD 8-way (r16), reader-spin + raw-C relayout (r18).
#define FOR16(X) X(0) X(1) X(2) X(3) X(4) X(5) X(6) X(7) X(8) X(9) X(10) X(11) X(12) X(13) X(14) X(15)

#define AGLD(p) __hip_atomic_load((p), __ATOMIC_RELAXED, __HIP_MEMORY_SCOPE_AGENT)
#define AGST(p, v) __hip_atomic_store((p), (v), __ATOMIC_RELAXED, __HIP_MEMORY_SCOPE_AGENT)
#define AGADD(p) __hip_atomic_fetch_add((p), 1, __ATOMIC_RELAXED, __HIP_MEMORY_SCOPE_AGENT)

struct IpotLds {
  float xs[128];
  float ys[NN];
  _Float16 zs[NN];
  _Float16 csh[8][520];
  float wred[8];
};
union MainLds {
  _Float16 Bs[2][16384];   // 64KB: [buf][row 0..511][4 slots x 8 halfs], row stride 64B
  _Float16 At[4][8192];    // 64KB: transpose regions (16KB per wave-slot)
  float mm[16];
  int mmi[16];
  IpotLds ip;
};

__global__ __launch_bounds__(512, 2) void k_main(const __half* __restrict__ xn,
                                                 const __half* __restrict__ yn,
                                                 int* __restrict__ cnt,
                                                 int* __restrict__ gmm,
                                                 unsigned* __restrict__ gpart,
                                                 float* __restrict__ gdist,
                                                 float* __restrict__ out) {
  __shared__ __align__(16) MainLds u;
  const int blk = blockIdx.x;
  const int b = blk & 63, qq = blk >> 6;
  const int tid = threadIdx.x;
  const int sv = tid >> 6, lane = tid & 63;
  const int fr = lane & 15;
  const int r0 = sv * 16;
  const int c0 = lane * 8;
  const int kg = lane >> 4;                        // k-group 0..3
  const int g8 = kg * 8;                           // k-offset in halfs (global A reads)
  const int rslot = (kg ^ ((fr >> 1) & 3)) * 8;    // swizzled B-read slot (halfs)
  const __half* xnb = xn + ((size_t)b * NN + qq * 128 + sv * 16) * DD;  // wave's 16 rows
  const __half* ynb = yn + (size_t)b * NN * DD;

  // ================= GEMM: acc[c] = C-tile rows 16sv.., cols 16c.. =================
  f32x4 acc[32] = {};
  const int srcq = ((lane & 3) ^ ((lane >> 3) & 3)) * 8;   // swizzle via source chunk
#define STAGE(bf, kk) { \
    _Pragma("unroll") \
    for (int j = 0; j < 4; ++j) { \
      const __half* ys_ = ynb + (size_t)(128 * j + sv * 16 + (lane >> 2)) * DD + (kk) + srcq; \
      glds16(ys_, (char*)u.Bs[bf] + j * 8192 + sv * 1024); \
    } }
  int buf = 0;
  STAGE(0, 0)
  half8 afp = *(const half8*)(xnb + (size_t)fr * DD + g8);
  for (int kk = 0; kk < DD; kk += 32) {
    __syncthreads();                       // drains vmcnt: Bs[buf] resident
    if (kk + 32 < DD) STAGE(buf ^ 1, kk + 32)
    half8 afc = afp;
    if (kk + 32 < DD) afp = *(const half8*)(xnb + (size_t)fr * DD + (kk + 32) + g8);
    #pragma unroll
    for (int c = 0; c < 32; ++c) {
      half8 bf = *(const half8*)(&u.Bs[buf][(16 * c + fr) * 32 + rslot]);
      acc[c] = __builtin_amdgcn_mfma_f32_16x16x32_f16(afc, bf, acc[c], 0, 0, 0);
    }
    buf ^= 1;
  }

  // ================= global min/max -> thr (two-level barrier) =================
  float vmin = 1e30f, vmax = -1e30f;
  #pragma unroll
  for (int c = 0; c < 32; ++c) {
    #pragma unroll
    for (int r2 = 0; r2 < 4; ++r2) {
      float val = 1.0f - acc[c][r2];
      vmin = fminf(vmin, val); vmax = fmaxf(vmax, val);
    }
  }
  #pragma unroll
  for (int m = 1; m < 64; m <<= 1) {
    vmin = fminf(vmin, __shfl_xor(vmin, m, 64));
    vmax = fmaxf(vmax, __shfl_xor(vmax, m, 64));
  }
  __syncthreads();                          // Bs dead; union repurposed
  if (lane == 0) { u.mm[sv] = vmin; u.mm[8 + sv] = vmax; }
  __syncthreads();
  if (tid == 0) {
    float bm = u.mm[0], bx = u.mm[8];
    #pragma unroll
    for (int g = 1; g < 8; ++g) { bm = fminf(bm, u.mm[g]); bx = fmaxf(bx, u.mm[8 + g]); }
    AGST(gmm + blk, (unsigned)f2ord(bm));
    AGST(gmm + 256 + blk, (unsigned)f2ord(bx));
  }
  __syncthreads();                          // tid0's gmm stores drained
  if (tid == 0) {
    int* c1p = cnt + 1024 + b * 16;         // L1: per-batch (4 contenders, proven cheap)
    AGADD(c1p);
    while (__hip_atomic_load(c1p, __ATOMIC_RELAXED, __HIP_MEMORY_SCOPE_AGENT) < 4)
      __builtin_amdgcn_s_sleep(1);
    if (qq == 0) AGADD(cnt + 2048);         // L2: only 64 reps touch the global line
    while (__hip_atomic_load(cnt + 2048, __ATOMIC_RELAXED, __HIP_MEMORY_SCOPE_AGENT) < 64)
      __builtin_amdgcn_s_sleep(8);
  }
  __syncthreads();
  {
    int mo = (int)AGLD(gmm + tid);          // tid<256: min-ords; tid>=256: max-ords
    #pragma unroll
    for (int m = 1; m < 64; m <<= 1) {
      int o = __shfl_xor(mo, m, 64);
      mo = (sv < 4) ? (mo < o ? mo : o) : (mo > o ? mo : o);
    }
    if (lane == 0) u.mmi[sv] = mo;
  }
  __syncthreads();
  int gmnord = u.mmi[0], gmxord = u.mmi[4];
  #pragma unroll
  for (int g = 1; g < 4; ++g) {
    gmnord = gmnord < u.mmi[g] ? gmnord : u.mmi[g];
    gmxord = gmxord > u.mmi[4 + g] ? gmxord : u.mmi[4 + g];
  }
  const float gmn = ord2f(gmnord);
  const float gmx = ord2f(gmxord);
  const float thr = gmn + 0.1f * (gmx - gmn);

  // ================= A = exp(-2 relu(C-thr)); intra-wave relayout via LDS ==========
#define DECLAM(r) half8 A##r, M##r;
  FOR16(DECLAM)

#define TWRITE { \
    _Float16* reg_ = u.At[sv & 3]; \
    const int q_ = lane >> 4; \
    _Pragma("unroll") \
    for (int c = 0; c < 32; ++c) { \
      _Pragma("unroll") \
      for (int r2 = 0; r2 < 4; ++r2) { \
        float val_ = 1.0f - acc[c][r2]; \
        float a_ = __expf(-2.0f * fmaxf(val_ - thr, 0.0f)); \
        int off_ = (((4 * q_ + r2) * 1024 + (16 * c + fr) * 2) ^ (q_ << 4)) >> 1; \
        reg_[off_] = (_Float16)a_; \
      } \
    } }

#define TREAD(r) { \
    A##r = *(const half8*)((const char*)u.At[sv & 3] + \
            (((r) * 1024 + lane * 16) ^ ((((r) >> 2) & 3) << 4))); \
    M##r = A##r; }

  __syncthreads();
  if (sv < 4) TWRITE
  __syncthreads();
  if (sv < 4) { FOR16(TREAD) }
  __syncthreads();
  if (sv >= 4) TWRITE
  __syncthreads();
  if (sv >= 4) { FOR16(TREAD) }
  __syncthreads();

  // ================= ipot state init =================
  if (tid < 256) *(half2v*)(u.ip.zs + 2 * tid) = (half2v){(_Float16)1.0f, (_Float16)1.0f};
  u.ip.ys[tid] = 1.0f;
  __syncthreads();

  int* mycnt = cnt + b * 16;

  // ================= 30 iterations (proven exchange; UPDM overlapped) ====
  #pragma unroll 1
  for (int t = 1; t <= 30; ++t) {
    half8 zv = *(const half8*)(u.ip.zs + c0);
    float rp16[16];
#define ROWP(r) { \
      half8 p = M##r * zv; \
      half4 q = p.lo + p.hi; \
      half2v q2 = q.lo + q.hi; \
      rp16[r] = (float)q2.x + (float)q2.y; }
    FOR16(ROWP)
    float c8[8];
    #pragma unroll
    for (int i = 0; i < 8; ++i) {
      float keep = (lane & 1) ? rp16[2*i+1] : rp16[2*i];
      float send = (lane & 1) ? rp16[2*i]   : rp16[2*i+1];
      c8[i] = keep + __shfl_xor(send, 1, 64);
    }
    float c4[4];
    #pragma unroll
    for (int i = 0; i < 4; ++i) {
      float keep = (lane & 2) ? c8[2*i+1] : c8[2*i];
      float send = (lane & 2) ? c8[2*i]   : c8[2*i+1];
      c4[i] = keep + __shfl_xor(send, 2, 64);
    }
    float d2[2];
    #pragma unroll
    for (int i = 0; i < 2; ++i) {
      float keep = (lane & 4) ? c4[2*i+1] : c4[2*i];
      float send = (lane & 4) ? c4[2*i]   : c4[2*i+1];
      d2[i] = keep + __shfl_xor(send, 4, 64);
    }
    float c1;
    {
      float keep = (lane & 8) ? d2[1] : d2[0];
      float send = (lane & 8) ? d2[0] : d2[1];
      c1 = keep + __shfl_xor(send, 8, 64);
    }
    c1 += __shfl_xor(c1, 16, 64);
    c1 += __shfl_xor(c1, 32, 64);
    if (lane < 16) u.ip.xs[r0 + lane] = 1.0f / c1;
    half8 cac = (half8)(_Float16)0.0f;
#define COLP(r) { _Float16 xh = (_Float16)u.ip.xs[r0 + r]; cac += M##r * xh; }
    FOR16(COLP)
    *(half8*)(&u.ip.csh[sv][c0]) = cac;
    __syncthreads();
    // ---- reduce + ISSUE partial stores, then UPDM covers their latency ----
    unsigned* gp = gpart + ((size_t)((t & 1) * 256 + blk) * 256);
    if (tid < 256) {
      float a0 = 0.0f, a1 = 0.0f;
      #pragma unroll
      for (int g = 0; g < 8; ++g) {
        half2v pv = *(const half2v*)(&u.ip.csh[g][2 * tid]);
        a0 += (float)pv.x; a1 += (float)pv.y;
      }
      __half2 ph = __floats2half2_rn(a0, a1);
      AGST(gp + tid, *reinterpret_cast<unsigned*>(&ph));
    }
#define UPDM(r) M##r *= A##r;
    if (t < 30) { FOR16(UPDM) }             // register-only; overlaps store flight
    __syncthreads();  // vmcnt(0) before s_barrier: stores at coherent point
    if (tid == 0) {
      AGADD(mycnt);
      while (__hip_atomic_load(mycnt, __ATOMIC_RELAXED, __HIP_MEMORY_SCOPE_AGENT) < 4 * t)
        __builtin_amdgcn_s_sleep(1);
    }
    __syncthreads();
    if (tid < 256) {
      float a0 = 0.0f, a1 = 0.0f;
      #pragma unroll
      for (int q2 = 0; q2 < 4; ++q2) {
        unsigned v = AGLD(gpart + ((size_t)((t & 1) * 256 + b + 64 * q2) * 256) + tid);
        __half2 h = *reinterpret_cast<__half2*>(&v);
        float2 fv = __half22float2(h);
        a0 += fv.x; a1 += fv.y;
      }
      float yo0 = u.ip.ys[2 * tid], yo1 = u.ip.ys[2 * tid + 1];
      float y0 = 1.0f / a0;
      float y1 = 1.0f / a1;
      *(half2v*)(u.ip.zs + 2 * tid) = (half2v){(_Float16)(y0 * y0 / yo0), (_Float16)(y1 * y1 / yo1)};
      u.ip.ys[2 * tid] = y0; u.ip.ys[2 * tid + 1] = y1;
    }
    __syncthreads();
  }

  // ================= dist partial: C' = -0.5 ln A (regs) =================
  float contrib = 0.0f;
#define FINP(r) { \
    float rowacc = 0.0f; \
    rowacc += -0.34657359f * __log2f((float)A##r.s0) * (float)M##r.s0 * u.ip.ys[c0 + 0]; \
    rowacc += -0.34657359f * __log2f((float)A##r.s1) * (float)M##r.s1 * u.ip.ys[c0 + 1]; \
    rowacc += -0.34657359f * __log2f((float)A##r.s2) * (float)M##r.s2 * u.ip.ys[c0 + 2]; \
    rowacc += -0.34657359f * __log2f((float)A##r.s3) * (float)M##r.s3 * u.ip.ys[c0 + 3]; \
    rowacc += -0.34657359f * __log2f((float)A##r.s4) * (float)M##r.s4 * u.ip.ys[c0 + 4]; \
    rowacc += -0.34657359f * __log2f((float)A##r.s5) * (float)M##r.s5 * u.ip.ys[c0 + 5]; \
    rowacc += -0.34657359f * __log2f((float)A##r.s6) * (float)M##r.s6 * u.ip.ys[c0 + 6]; \
    rowacc += -0.34657359f * __log2f((float)A##r.s7) * (float)M##r.s7 * u.ip.ys[c0 + 7]; \
    contrib += rowacc * u.ip.xs[r0 + r]; }
  FOR16(FINP)
  #pragma unroll
  for (int m = 1; m < 64; m <<= 1) contrib += __shfl_xor(contrib, m, 64);
  if (lane == 0) u.ip.wred[sv] = contrib;
  __syncthreads();
  if (tid == 0) {
    float s2 = 0.0f;
    #pragma unroll
    for (int g = 0; g < 8; ++g) s2 += u.ip.wred[g];
    AGST(gdist + blk, s2);
  }
  // ================= merged final: global barrier -> block 0 reduces =================
  __syncthreads();                          // drains tid0's gdist store
  if (tid == 0) AGADD(cnt + 2048);          // counter now reaches 64 + 256 = 320
  if (blk == 0) {
    if (tid == 0) {
      while (__hip_atomic_load(cnt + 2048, __ATOMIC_RELAXED, __HIP_MEMORY_SCOPE_AGENT) < 320)
        __builtin_amdgcn_s_sleep(8);
    }
    __syncthreads();
    if (tid < 64) {
      float v = AGLD(gdist + tid) + AGLD(gdist + tid + 64)
              + AGLD(gdist + tid + 128) + AGLD(gdist + tid + 192);
      #pragma unroll
      for (int m = 1; m < 64; m <<= 1) v += __shfl_xor(v, m, 64);
      if (tid == 0) out[0] = -v * (1.0f / (64.0f * 512.0f));
    }
  }
}

extern "C" void kernel_launch(void* const* d_in, const int* in_sizes, int n_in,
                              void* d_out, int out_size, void* d_ws, size_t ws_size,
                              hipStream_t stream) {
  const float* f1 = (const float*)d_in[0];
  const float* f2 = (const float*)d_in[1];
  char* ws = (char*)d_ws;
  __half* xn   = (__half*)(ws + 0);                  // 50,331,648 B
  __half* yn   = (__half*)(ws + 50331648);           // 50,331,648 B
  unsigned* gpart = (unsigned*)(ws + 100663296);     // 512KB fp16-packed partials
  int*   cnt   = (int*)(ws + 167772160);             // loop cnts | minmax L1 | [2048] global
  int*   gmm   = (int*)(ws + 167772160 + 16384);     // 512 ints block min/max
  float* gdist = (float*)(ws + 167772160 + 16384 + 2048);  // 256 floats

  k_norm<<<16384, 256, 0, stream>>>(f1, f2, xn, yn, cnt);
  k_main<<<256, 512, 0, stream>>>(xn, yn, cnt, (int*)gmm, gpart, gdist, (float*)d_out);
}